// Round 1
// baseline (1653.626 us; speedup 1.0000x reference)
//
#include <hip/hip_runtime.h>

#define TAILB 12.0f

__device__ __forceinline__ float softplus_f(float z) {
    // log1p(exp(z)); stable for large z. For very negative z, log1pf(exp(z)) ~ exp(z): fine.
    return (z > 15.f) ? z : log1pf(__expf(z));
}

__global__ __launch_bounds__(256)
void rqs_fused(const float* __restrict__ inp, const float* __restrict__ cond,
               const float* __restrict__ W1, const float* __restrict__ b1,
               const float* __restrict__ W2, const float* __restrict__ b2,
               const float* __restrict__ W3, const float* __restrict__ b3,
               float* __restrict__ out, int B)
{
    int tid = blockIdx.x * 256 + threadIdx.x;
    if (tid >= B) return;

    const float4 xi = reinterpret_cast<const float4*>(inp)[tid];
    float x0 = xi.x, x1 = xi.y, x2 = xi.z, x3 = xi.w;
    float c = cond[tid];
    float ld = 0.f;

    #pragma unroll 1
    for (int l = 0; l < 4; ++l) {
        // MASK_IDX: l0:(0,2) l1:(1,3) l2:(0,1) l3:(2,3)  (wave-uniform branches on l)
        float m0 = (l == 0 || l == 2) ? x0 : (l == 1) ? x1 : x2;
        float m1 = (l == 0) ? x2 : (l == 1) ? x3 : (l == 2) ? x1 : x3;

        const float* w1  = W1 + l * 384;     // [128,3]
        const float* bb1 = b1 + l * 128;
        const float* w2  = W2 + l * 16384;   // [128,128]
        const float* bb2 = b2 + l * 128;
        const float* w3  = W3 + l * 5888;    // [46,128]
        const float* bb3 = b3 + l * 46;

        // ---- phase 1: h1 = relu(W1 @ m + b1), fully in registers ----
        float h1[128];
        #pragma unroll
        for (int k = 0; k < 128; ++k) {
            float v = fmaf(w1[k * 3 + 0], m0,
                      fmaf(w1[k * 3 + 1], m1,
                      fmaf(w1[k * 3 + 2], c, bb1[k])));
            h1[k] = fmaxf(v, 0.f);
        }

        // ---- phase 2: h2 chunks of 8, consumed immediately into params[46] ----
        float pr[46];
        #pragma unroll
        for (int p = 0; p < 46; ++p) pr[p] = bb3[p];

        #pragma unroll 1
        for (int jc = 0; jc < 128; jc += 8) {
            float h2c[8];
            #pragma unroll
            for (int jj = 0; jj < 8; ++jj) {
                const float* wr = w2 + (jc + jj) * 128;
                float a = bb2[jc + jj];
                #pragma unroll
                for (int k = 0; k < 128; ++k) a = fmaf(wr[k], h1[k], a);
                h2c[jj] = fmaxf(a, 0.f);
            }
            #pragma unroll
            for (int p = 0; p < 46; ++p) {
                const float* wc = w3 + p * 128 + jc;
                float a = pr[p];
                #pragma unroll
                for (int jj = 0; jj < 8; ++jj) a = fmaf(wc[jj], h2c[jj], a);
                pr[p] = a;
            }
        }

        // ---- phase 3: RQS spline on the two transformed dims ----
        // tp[b,f,p] = params[b, p*2+f]; uw p=0..7, uh p=8..15, ud p=16..22
        float ynew[2];
        float ladsum = 0.f;
        #pragma unroll
        for (int f = 0; f < 2; ++f) {
            // INV_IDX: l0:(1,3) l1:(0,2) l2:(2,3) l3:(0,1)
            float xin;
            if (f == 0) xin = (l == 0) ? x1 : (l == 1) ? x0 : (l == 2) ? x2 : x0;
            else        xin = (l == 0) ? x3 : (l == 1) ? x2 : (l == 2) ? x3 : x1;

            float uw[8], uh[8];
            #pragma unroll
            for (int k = 0; k < 8; ++k) { uw[k] = pr[2 * k + f]; uh[k] = pr[16 + 2 * k + f]; }
            float d[9];
            d[0] = 1.f; d[8] = 1.f;   // softplus(log(exp(1-MIN_D)-1)) + MIN_D == 1.0 exactly
            #pragma unroll
            for (int k = 1; k < 8; ++k) d[k] = 1e-6f + softplus_f(pr[32 + 2 * (k - 1) + f]);

            bool inside = (xin >= -TAILB) && (xin <= TAILB);
            float xc = fminf(fmaxf(xin, -TAILB), TAILB);

            float mw = uw[0], mh = uh[0];
            #pragma unroll
            for (int k = 1; k < 8; ++k) { mw = fmaxf(mw, uw[k]); mh = fmaxf(mh, uh[k]); }
            float ew[8], eh[8], sw = 0.f, sh = 0.f;
            #pragma unroll
            for (int k = 0; k < 8; ++k) {
                ew[k] = __expf(uw[k] - mw); sw += ew[k];
                eh[k] = __expf(uh[k] - mh); sh += eh[k];
            }
            const float c1 = 1.f - 8e-6f;
            float isw = c1 / sw, ish = c1 / sh;

            // walk the 8 bins; select the last bin with xc >= cumw[k]
            float cum_w = 0.f, cum_h = 0.f;
            float cwk = -TAILB, chk = -TAILB;
            float s_cw = -TAILB, s_w = 2.f * TAILB, s_ch = -TAILB, s_h = 2.f * TAILB;
            float s_d0 = 1.f, s_d1 = d[1];
            #pragma unroll
            for (int k = 0; k < 8; ++k) {
                cum_w += fmaf(ew[k], isw, 1e-6f);
                cum_h += fmaf(eh[k], ish, 1e-6f);
                float cwn = (k == 7) ? TAILB : fmaf(2.f * TAILB, cum_w, -TAILB);
                float chn = (k == 7) ? TAILB : fmaf(2.f * TAILB, cum_h, -TAILB);
                bool ge = (xc >= cwk);
                s_cw = ge ? cwk : s_cw;  s_w = ge ? (cwn - cwk) : s_w;
                s_ch = ge ? chk : s_ch;  s_h = ge ? (chn - chk) : s_h;
                s_d0 = ge ? d[k] : s_d0; s_d1 = ge ? d[k + 1] : s_d1;
                cwk = cwn; chk = chn;
            }

            float th   = (xc - s_cw) / s_w;
            float delta = s_h / s_w;
            float omt  = 1.f - th;
            float tomt = th * omt;
            float num  = s_h * fmaf(delta, th * th, s_d0 * tomt);
            float den  = fmaf(s_d0 + s_d1 - 2.f * delta, tomt, delta);
            float y    = s_ch + num / den;
            float dnum = delta * delta * (s_d1 * th * th + 2.f * delta * tomt + s_d0 * omt * omt);
            float lad  = __logf(dnum) - 2.f * __logf(den);

            ynew[f] = inside ? y : xin;
            ladsum += inside ? lad : 0.f;
        }

        if (l == 0)      { x1 = ynew[0]; x3 = ynew[1]; }
        else if (l == 1) { x0 = ynew[0]; x2 = ynew[1]; }
        else if (l == 2) { x2 = ynew[0]; x3 = ynew[1]; }
        else             { x0 = ynew[0]; x1 = ynew[1]; }
        ld += ladsum;
    }

    float4 xo; xo.x = x0; xo.y = x1; xo.z = x2; xo.w = x3;
    reinterpret_cast<float4*>(out)[tid] = xo;
    out[(size_t)B * 4 + tid] = ld;
}

extern "C" void kernel_launch(void* const* d_in, const int* in_sizes, int n_in,
                              void* d_out, int out_size, void* d_ws, size_t ws_size,
                              hipStream_t stream) {
    const float* inp  = (const float*)d_in[0];
    const float* cond = (const float*)d_in[1];
    const float* W1   = (const float*)d_in[2];
    const float* b1   = (const float*)d_in[3];
    const float* W2   = (const float*)d_in[4];
    const float* b2   = (const float*)d_in[5];
    const float* W3   = (const float*)d_in[6];
    const float* b3   = (const float*)d_in[7];
    float* out = (float*)d_out;
    int B = in_sizes[0] / 4;
    int blocks = (B + 255) / 256;
    hipLaunchKernelGGL(rqs_fused, dim3(blocks), dim3(256), 0, stream,
                       inp, cond, W1, b1, W2, b2, W3, b3, out, B);
}